// Round 7
// baseline (463.996 us; speedup 1.0000x reference)
//
#include <hip/hip_runtime.h>

// expRNN/modReLU recurrence, B=8192, T=784, I=1, H=30, C=10.
//
// Round 12 = R11 (393us, passed) + sched_barrier(0) phase fences.
// Refined model: at 1 wave/CU only 1/4 SIMDs is active; one 16x16x32 MFMA
// holds its SIMD's matrix pipe ~19.4 cyc (2075TF ubench / 1024 SIMDs).
// Per SKEWSTEP floor = max(24 MFMA x 19.4 = 466, ~170 VALU x 2 = 340) cyc
// -> 152us best case. Measured 1203 cyc/SKEWSTEP: the compiler re-clusters
// my skewed phases (proven by R10: source ILP2 gave 8%), exposing MFMA
// dest-read hazards/latency with no sibling wave to hide them.
// Fix: __builtin_amdgcn_sched_barrier(0) at each phase boundary pins
// M(c1) -> V(c0) -> M(c0,t+1) -> V(c1) in the emitted schedule. Every acc
// is then consumed a full phase (~150+ cyc) after its MFMA cluster, and
// every FB write has a phase before its MFMA read. Zero added instructions.
// Predict: 180-240us, MfmaUtil 13-17, VALUBusy 30-40, VGPR ~72.
// Decision: <10% change => stall is intrinsic single-wave MFMA latency ->
// next: fp16 2-split/3-product (233cyc floor) + per-column rescale.

#define T_STEPS 784
#define NBATCH  8192
#define NH      30
#define NC      10
#define BPC     16            // batches per chunk (16x16 tile)
#define CPB     2             // chunks per wave
#define BPB     (BPC * CPB)   // 32 batches per block

typedef float  f32x4 __attribute__((ext_vector_type(4)));
typedef short  s16x8 __attribute__((ext_vector_type(8)));
typedef int    i32x4 __attribute__((ext_vector_type(4)));

#define MFMA16(a, b, c) __builtin_amdgcn_mfma_f32_16x16x32_bf16(a, b, c, 0, 0, 0)
#define SBAR() __builtin_amdgcn_sched_barrier(0)

__device__ __forceinline__ int cvt_pk_bf16(float lo, float hi) {
    int d;
    asm("v_cvt_pk_bf16_f32 %0, %1, %2" : "=v"(d) : "v"(lo), "v"(hi));
    return d;
}
__device__ __forceinline__ float rne_bf16(float x) {
    unsigned u = __float_as_uint(x);
    u = (u + 0x7fffu + ((u >> 16) & 1u)) & 0xffff0000u;
    return __uint_as_float(u);
}
__device__ __forceinline__ float lo16f(int p) { return __uint_as_float(((unsigned)p) << 16); }
__device__ __forceinline__ float hi16f(int p) { return __uint_as_float(((unsigned)p) & 0xffff0000u); }

__device__ __forceinline__ s16x8 pack8(const float* v) {
    i32x4 t;
    t.x = cvt_pk_bf16(v[0], v[1]);
    t.y = cvt_pk_bf16(v[2], v[3]);
    t.z = cvt_pk_bf16(v[4], v[5]);
    t.w = cvt_pk_bf16(v[6], v[7]);
    return __builtin_bit_cast(s16x8, t);
}

// MFMA phase: 12 MFMAs, 4 chains of depth 3.
#define MPHASE(A0, A1, A2, A3, FB) { \
    const f32x4 zz4 = {0.0f, 0.0f, 0.0f, 0.0f}; \
    A0 = MFMA16(wA[0][0], FB[0], zz4); \
    A1 = MFMA16(wA[1][0], FB[1], zz4); \
    A2 = MFMA16(wA[0][1], FB[0], zz4); \
    A3 = MFMA16(wA[1][1], FB[1], zz4); \
    A0 = MFMA16(wA[0][0], FB[1], A0); \
    A1 = MFMA16(wA[1][0], FB[0], A1); \
    A2 = MFMA16(wA[0][1], FB[1], A2); \
    A3 = MFMA16(wA[1][1], FB[0], A3); \
    A0 = MFMA16(wA[0][0], FB[2], A0); \
    A1 = MFMA16(wA[2][0], FB[0], A1); \
    A2 = MFMA16(wA[0][1], FB[2], A2); \
    A3 = MFMA16(wA[2][1], FB[0], A3); \
}

// VALU phase: modReLU + 3-level split + x insert (k=30 on g==3, word3.lo16).
#define VPHASE(A0, A1, A2, A3, FB, HST, XNEXT) { \
    _Pragma("unroll") \
    for (int j = 0; j < 4; ++j) { \
        float z = A0[j] + A1[j]; \
        HST[j] = copysignf(fmaxf(fabsf(z) + bmr[0][j], 0.0f), z); \
    } \
    _Pragma("unroll") \
    for (int j = 0; j < 4; ++j) { \
        float z = A2[j] + A3[j]; \
        HST[4 + j] = copysignf(fmaxf(fabsf(z) + bmr[1][j], 0.0f), z); \
    } \
    int P1[4], P2[4], P3[4]; \
    _Pragma("unroll") \
    for (int q = 0; q < 4; ++q) { \
        float pa = HST[2 * q], pb = HST[2 * q + 1]; \
        int p1 = cvt_pk_bf16(pa, pb); \
        float ra = pa - lo16f(p1), rb = pb - hi16f(p1); \
        int p2 = cvt_pk_bf16(ra, rb); \
        int p3 = cvt_pk_bf16(ra - lo16f(p2), rb - hi16f(p2)); \
        P1[q] = p1; P2[q] = p2; P3[q] = p3; \
    } \
    int xs1 = cvt_pk_bf16((XNEXT), 0.0f); \
    float xr1 = (XNEXT) - lo16f(xs1); \
    int xs2 = cvt_pk_bf16(xr1, 0.0f); \
    int xs3 = cvt_pk_bf16(xr1 - lo16f(xs2), 0.0f); \
    i32x4 t_; \
    t_.x = P1[0]; t_.y = P1[1]; t_.z = P1[2]; t_.w = g3 ? xs1 : P1[3]; \
    FB[0] = __builtin_bit_cast(s16x8, t_); \
    t_.x = P2[0]; t_.y = P2[1]; t_.z = P2[2]; t_.w = g3 ? xs2 : P2[3]; \
    FB[1] = __builtin_bit_cast(s16x8, t_); \
    t_.x = P3[0]; t_.y = P3[1]; t_.z = P3[2]; t_.w = g3 ? xs3 : P3[3]; \
    FB[2] = __builtin_bit_cast(s16x8, t_); \
}

// skewed step with pinned schedule: fences forbid cross-phase reordering.
#define SKEWSTEP(XN0, XN1) { \
    MPHASE(c10, c11, c12, c13, fB1)               /* chunk1 step t    */ \
    SBAR(); \
    VPHASE(c00, c01, c02, c03, fB0, hst0, (XN0))  /* finish c0 t      */ \
    SBAR(); \
    MPHASE(c00, c01, c02, c03, fB0)               /* chunk0 step t+1  */ \
    SBAR(); \
    VPHASE(c10, c11, c12, c13, fB1, hst1, (XN1))  /* finish c1 t      */ \
    SBAR(); \
}

__global__ __launch_bounds__(64, 1)
void rnn_mfma_skew(const float* __restrict__ inp,    // [B, T, 1]
                   const float* __restrict__ W_ih,   // [H, 1]
                   const float* __restrict__ W_hh,   // [H, H]
                   const float* __restrict__ b_mod,  // [H]
                   const float* __restrict__ W_lin,  // [C, H]
                   const float* __restrict__ b_lin,  // [C]
                   float* __restrict__ out)          // [B, C]
{
    __shared__ float hfin[BPB * 33];   // 4.2 KB, stride 33

    const int l   = threadIdx.x;
    const int blk = blockIdx.x;
    const int n   = l & 15;            // B/D column (batch in chunk); A row idx
    const int g   = l >> 4;            // lane group: owns k/rows 8g..8g+7
    const bool g3 = (g == 3);

    // ---- x pointers + first two float4 buffers (used from t=0 / t=4) ----
    const float* xr0 = inp + (size_t)(blk * BPB + 0 * BPC + n) * T_STEPS;
    const float* xr1 = inp + (size_t)(blk * BPB + 1 * BPC + n) * T_STEPS;
    float4 xA0 = *(const float4*)(xr0);
    float4 xA1 = *(const float4*)(xr1);
    float4 xB0 = *(const float4*)(xr0 + 4);
    float4 xB1 = *(const float4*)(xr1 + 4);

    // ---- A-frags: permuted row-slices, 3 W-levels, x column at k=30 ----
    // slice s holds true rows R = (n&3) + 8*(n>>2) + 4s; k = 8g + e.
    // k==30 -> W_ih (x slot); k==31 -> 0.  (verbatim R10/R11, HW-verified)
    s16x8 wA[3][2];
    #pragma unroll
    for (int s = 0; s < 2; ++s) {
        const int R = (n & 3) + 8 * (n >> 2) + 4 * s;
        float w1f[8], w2f[8], w3f[8];
        #pragma unroll
        for (int e = 0; e < 8; ++e) {
            const int k = 8 * g + e;
            float w = 0.0f;
            if (R < NH) {
                if (k < NH)       w = W_hh[R * NH + k];
                else if (k == NH) w = W_ih[R];         // k==30: x column
            }
            float a1 = rne_bf16(w);  float r1 = w - a1;
            float a2 = rne_bf16(r1); float r2 = r1 - a2;
            w1f[e] = a1; w2f[e] = a2; w3f[e] = r2;     // lvl3 RNE'd by pack8
        }
        wA[0][s] = pack8(w1f);
        wA[1][s] = pack8(w2f);
        wA[2][s] = pack8(w3f);
    }

    // modReLU bias per acc reg: slice s reg j <-> true row 8g + 4s + j
    float bmr[2][4];
    #pragma unroll
    for (int s = 0; s < 2; ++s)
        #pragma unroll
        for (int j = 0; j < 4; ++j) {
            const int R = 8 * g + 4 * s + j;
            bmr[s][j] = (R < NH) ? b_mod[R] : 0.0f;
        }

    // ---- initial state: h=0, x[0] at k=30 (g==3, word3 lo16) ----
    s16x8 fB0[3], fB1[3];
    {
        int i1 = cvt_pk_bf16(xA0.x, 0.0f);
        float r1 = xA0.x - lo16f(i1);
        int i2 = cvt_pk_bf16(r1, 0.0f);
        int i3 = cvt_pk_bf16(r1 - lo16f(i2), 0.0f);
        i32x4 t; t.x = 0; t.y = 0; t.z = 0;
        t.w = g3 ? i1 : 0; fB0[0] = __builtin_bit_cast(s16x8, t);
        t.w = g3 ? i2 : 0; fB0[1] = __builtin_bit_cast(s16x8, t);
        t.w = g3 ? i3 : 0; fB0[2] = __builtin_bit_cast(s16x8, t);
    }
    {
        int i1 = cvt_pk_bf16(xA1.x, 0.0f);
        float r1 = xA1.x - lo16f(i1);
        int i2 = cvt_pk_bf16(r1, 0.0f);
        int i3 = cvt_pk_bf16(r1 - lo16f(i2), 0.0f);
        i32x4 t; t.x = 0; t.y = 0; t.z = 0;
        t.w = g3 ? i1 : 0; fB1[0] = __builtin_bit_cast(s16x8, t);
        t.w = g3 ? i2 : 0; fB1[1] = __builtin_bit_cast(s16x8, t);
        t.w = g3 ? i3 : 0; fB1[2] = __builtin_bit_cast(s16x8, t);
    }

    float hst0[8], hst1[8];
    f32x4 c00, c01, c02, c03, c10, c11, c12, c13;

    // prologue: put chunk0's step 0 in flight
    MPHASE(c00, c01, c02, c03, fB0)
    SBAR();

    // ---- main recurrence: 196 iters x 4 skewed steps ----
    #pragma unroll 1
    for (int m = 0; m < T_STEPS / 4; ++m) {
        int mf = m + 2; if (mf > 195) mf = 195;      // clamp (tail values unused)
        float4 xC0 = *(const float4*)(xr0 + 4 * mf); // for iter m+2
        float4 xC1 = *(const float4*)(xr1 + 4 * mf);

        SKEWSTEP(xA0.y, xA1.y)   // t=4m+0, next x = x[4m+1]
        SKEWSTEP(xA0.z, xA1.z)   // t=4m+1
        SKEWSTEP(xA0.w, xA1.w)   // t=4m+2
        SKEWSTEP(xB0.x, xB1.x)   // t=4m+3, next x = x[4m+4]

        xA0 = xB0; xA1 = xB1;
        xB0 = xC0; xB1 = xC1;
    }
    // loop exits with hst0/hst1 = h(783); trailing in-flight MPHASE unused.

    // ---- stash final h: lane(g,n) owns true rows 8g..8g+7 of its batch ----
    #pragma unroll
    for (int j = 0; j < 8; ++j) {
        hfin[(0 * BPC + n) * 33 + 8 * g + j] = hst0[j];
        hfin[(1 * BPC + n) * 33 + 8 * g + j] = hst1[j];
    }
    __syncthreads();

    // ---- classifier: 320 outputs (32 batches x 10 classes), 5 per lane ----
    #pragma unroll
    for (int it = 0; it < 5; ++it) {
        const int kk = l + 64 * it;          // < 320
        const int bb = kk / 10;
        const int c  = kk - bb * 10;
        float acc = b_lin[c];
        #pragma unroll
        for (int i = 0; i < NH; ++i) {
            acc = fmaf(W_lin[c * NH + i], hfin[bb * 33 + i], acc);
        }
        out[((size_t)blk * BPB + bb) * NC + c] = acc;
    }
}

extern "C" void kernel_launch(void* const* d_in, const int* in_sizes, int n_in,
                              void* d_out, int out_size, void* d_ws, size_t ws_size,
                              hipStream_t stream) {
    const float* inp   = (const float*)d_in[0];
    const float* W_ih  = (const float*)d_in[1];
    const float* W_hh  = (const float*)d_in[2];
    const float* b_mod = (const float*)d_in[3];
    const float* W_lin = (const float*)d_in[4];
    const float* b_lin = (const float*)d_in[5];
    float* out = (float*)d_out;

    dim3 grid(NBATCH / BPB);   // 256 blocks, one wave each
    dim3 block(64);
    rnn_mfma_skew<<<grid, block, 0, stream>>>(inp, W_ih, W_hh, b_mod,
                                              W_lin, b_lin, out);
}

// Round 8
// 350.012 us; speedup vs baseline: 1.3257x; 1.3257x over previous
//
#include <hip/hip_runtime.h>

// expRNN/modReLU recurrence, B=8192, T=784, I=1, H=30, C=10.
//
// Round 13: latency-minimal single-chunk MFMA step.
// R12 (sched_barrier fences) changed nothing -> stall is intrinsic
// single-wave MFMA result latency (L_m >> 19cyc throughput number),
// exposed by in-order issue; ILP-in-one-wave cannot hide it (R10-R12).
// Changes vs R12, numerics preserved or improved:
//  - CPB=1: 512 blocks x 1 wave (2 waves/CU). Per-step issue halves;
//    the serial residual is paid once per wall-step.
//  - 12 INDEPENDENT MFMAs (C=0, chain depth 3 -> 1) + VALU tree-sum
//    (5 adds/slice). The 12-MFMA issue train (~72cyc) covers most of L_m.
//  - x-term now exact fp32 fmaf(wih, x, z) in the tree sum: deletes
//    x-split + cndmask inserts + k=30 column (x was bf16-split before;
//    now exact -> strictly better precision).
// W 3-split x h 3-split, 6 products/slice, verbatim R9-R12 (verified).
// Predict: 150-230us, MfmaUtil 10-15, VALUBusy 30-45, Occ ~6%, VGPR ~140.
// Decision: >=300us -> pivot to R5-VALU structure @ BPB=4/2048 blocks.

#define T_STEPS 784
#define NBATCH  8192
#define NH      30
#define NC      10
#define BPB     16            // batches per block (one 16x16 tile)

typedef float  f32x4 __attribute__((ext_vector_type(4)));
typedef short  s16x8 __attribute__((ext_vector_type(8)));
typedef int    i32x4 __attribute__((ext_vector_type(4)));

#define MFMA16(a, b, c) __builtin_amdgcn_mfma_f32_16x16x32_bf16(a, b, c, 0, 0, 0)

__device__ __forceinline__ int cvt_pk_bf16(float lo, float hi) {
    int d;
    asm("v_cvt_pk_bf16_f32 %0, %1, %2" : "=v"(d) : "v"(lo), "v"(hi));
    return d;
}
__device__ __forceinline__ float rne_bf16(float x) {
    unsigned u = __float_as_uint(x);
    u = (u + 0x7fffu + ((u >> 16) & 1u)) & 0xffff0000u;
    return __uint_as_float(u);
}
__device__ __forceinline__ float lo16f(int p) { return __uint_as_float(((unsigned)p) << 16); }
__device__ __forceinline__ float hi16f(int p) { return __uint_as_float(((unsigned)p) & 0xffff0000u); }

__device__ __forceinline__ s16x8 pack8(const float* v) {
    i32x4 t;
    t.x = cvt_pk_bf16(v[0], v[1]);
    t.y = cvt_pk_bf16(v[2], v[3]);
    t.z = cvt_pk_bf16(v[4], v[5]);
    t.w = cvt_pk_bf16(v[6], v[7]);
    return __builtin_bit_cast(s16x8, t);
}

// One step: 12 independent MFMAs -> tree-sum + fp32 x-term -> modReLU ->
// 3-level split -> new B-fragments. XV = x[t] for this lane's batch.
#define STEP(XV) { \
    const f32x4 zz = {0.0f, 0.0f, 0.0f, 0.0f}; \
    f32x4 p0 = MFMA16(wA[0][0], fB[0], zz);   /* w1 h1  slice0 */ \
    f32x4 q0 = MFMA16(wA[0][1], fB[0], zz);   /* w1 h1  slice1 */ \
    f32x4 p1 = MFMA16(wA[0][0], fB[1], zz);   /* w1 h2 */ \
    f32x4 q1 = MFMA16(wA[0][1], fB[1], zz); \
    f32x4 p2 = MFMA16(wA[0][0], fB[2], zz);   /* w1 h3 */ \
    f32x4 q2 = MFMA16(wA[0][1], fB[2], zz); \
    f32x4 p3 = MFMA16(wA[1][0], fB[0], zz);   /* w2 h1 */ \
    f32x4 q3 = MFMA16(wA[1][1], fB[0], zz); \
    f32x4 p4 = MFMA16(wA[1][0], fB[1], zz);   /* w2 h2 */ \
    f32x4 q4 = MFMA16(wA[1][1], fB[1], zz); \
    f32x4 p5 = MFMA16(wA[2][0], fB[0], zz);   /* w3 h1 */ \
    f32x4 q5 = MFMA16(wA[2][1], fB[0], zz); \
    _Pragma("unroll") \
    for (int j = 0; j < 4; ++j) { \
        float z = ((p0[j] + p1[j]) + (p2[j] + p3[j])) + (p4[j] + p5[j]); \
        z = fmaf(wihr[0][j], (XV), z); \
        hst[j] = copysignf(fmaxf(fabsf(z) + bmr[0][j], 0.0f), z); \
    } \
    _Pragma("unroll") \
    for (int j = 0; j < 4; ++j) { \
        float z = ((q0[j] + q1[j]) + (q2[j] + q3[j])) + (q4[j] + q5[j]); \
        z = fmaf(wihr[1][j], (XV), z); \
        hst[4 + j] = copysignf(fmaxf(fabsf(z) + bmr[1][j], 0.0f), z); \
    } \
    int P1[4], P2[4], P3[4]; \
    _Pragma("unroll") \
    for (int q = 0; q < 4; ++q) { \
        float pa = hst[2 * q], pb = hst[2 * q + 1]; \
        int c1 = cvt_pk_bf16(pa, pb); \
        float ra = pa - lo16f(c1), rb = pb - hi16f(c1); \
        int c2 = cvt_pk_bf16(ra, rb); \
        int c3 = cvt_pk_bf16(ra - lo16f(c2), rb - hi16f(c2)); \
        P1[q] = c1; P2[q] = c2; P3[q] = c3; \
    } \
    i32x4 t_; \
    t_.x = P1[0]; t_.y = P1[1]; t_.z = P1[2]; t_.w = P1[3]; \
    fB[0] = __builtin_bit_cast(s16x8, t_); \
    t_.x = P2[0]; t_.y = P2[1]; t_.z = P2[2]; t_.w = P2[3]; \
    fB[1] = __builtin_bit_cast(s16x8, t_); \
    t_.x = P3[0]; t_.y = P3[1]; t_.z = P3[2]; t_.w = P3[3]; \
    fB[2] = __builtin_bit_cast(s16x8, t_); \
}

__global__ __launch_bounds__(64, 1)
void rnn_mfma1(const float* __restrict__ inp,    // [B, T, 1]
               const float* __restrict__ W_ih,   // [H, 1]
               const float* __restrict__ W_hh,   // [H, H]
               const float* __restrict__ b_mod,  // [H]
               const float* __restrict__ W_lin,  // [C, H]
               const float* __restrict__ b_lin,  // [C]
               float* __restrict__ out)          // [B, C]
{
    __shared__ float hfin[BPB * 33];   // 2.1 KB, stride 33

    const int l   = threadIdx.x;
    const int blk = blockIdx.x;
    const int n   = l & 15;            // batch column in tile; also A row idx
    const int g   = l >> 4;            // lane group: owns k/rows 8g..8g+7

    // ---- x pointer + first two float4 buffers ----
    const float* xr = inp + (size_t)(blk * BPB + n) * T_STEPS;
    float4 xA = *(const float4*)(xr);
    float4 xB = *(const float4*)(xr + 4);

    // ---- A-frags: permuted row-slices, 3 W-levels (k>=30 -> 0) ----
    // slice s holds true rows R = (n&3) + 8*(n>>2) + 4s; k = 8g + e.
    // Lane-group g's D regs then equal true rows 8g+4s+j = exactly the
    // k-range its next B-frag needs (verbatim R10-R12, HW-verified).
    s16x8 wA[3][2];
    #pragma unroll
    for (int s = 0; s < 2; ++s) {
        const int R = (n & 3) + 8 * (n >> 2) + 4 * s;
        float w1f[8], w2f[8], w3f[8];
        #pragma unroll
        for (int e = 0; e < 8; ++e) {
            const int k = 8 * g + e;
            float w = (R < NH && k < NH) ? W_hh[R * NH + k] : 0.0f;
            float a1 = rne_bf16(w);  float r1 = w - a1;
            float a2 = rne_bf16(r1); float r2 = r1 - a2;
            w1f[e] = a1; w2f[e] = a2; w3f[e] = r2;     // lvl3 RNE'd by pack8
        }
        wA[0][s] = pack8(w1f);
        wA[1][s] = pack8(w2f);
        wA[2][s] = pack8(w3f);
    }

    // per-acc-reg constants: slice s reg j <-> true row 8g + 4s + j
    float wihr[2][4], bmr[2][4];
    #pragma unroll
    for (int s = 0; s < 2; ++s)
        #pragma unroll
        for (int j = 0; j < 4; ++j) {
            const int R = 8 * g + 4 * s + j;
            wihr[s][j] = (R < NH) ? W_ih[R]  : 0.0f;
            bmr[s][j]  = (R < NH) ? b_mod[R] : 0.0f;
        }

    // ---- initial state: h = 0 (x enters via fp32 fmaf each step) ----
    s16x8 fB[3];
    {
        i32x4 zi = {0, 0, 0, 0};
        s16x8 z8 = __builtin_bit_cast(s16x8, zi);
        fB[0] = z8; fB[1] = z8; fB[2] = z8;
    }

    float hst[8];

    // ---- main recurrence: 196 iters x 4 steps, x float4 double-buffer ----
    #pragma unroll 1
    for (int m = 0; m < T_STEPS / 4; ++m) {
        int mf = m + 2; if (mf > 195) mf = 195;      // tail values unused
        float4 xC = *(const float4*)(xr + 4 * mf);

        STEP(xA.x)   // t = 4m
        STEP(xA.y)
        STEP(xA.z)
        STEP(xA.w)

        xA = xB;
        xB = xC;
    }
    // hst = h(784) final.

    // ---- stash final h: lane(g,n) owns true rows 8g+4s+j of batch n ----
    #pragma unroll
    for (int j = 0; j < 8; ++j) {
        hfin[n * 33 + 8 * g + 4 * (j >> 2) + (j & 3)] = hst[j];
    }
    __syncthreads();

    // ---- classifier: 160 outputs (16 batches x 10 classes) ----
    #pragma unroll
    for (int it = 0; it < 3; ++it) {
        const int kk = l + 64 * it;
        if (kk < BPB * NC) {
            const int bb = kk / 10;
            const int c  = kk - bb * 10;
            float acc = b_lin[c];
            #pragma unroll
            for (int i = 0; i < NH; ++i) {
                acc = fmaf(W_lin[c * NH + i], hfin[bb * 33 + i], acc);
            }
            out[((size_t)blk * BPB + bb) * NC + c] = acc;
        }
    }
}

extern "C" void kernel_launch(void* const* d_in, const int* in_sizes, int n_in,
                              void* d_out, int out_size, void* d_ws, size_t ws_size,
                              hipStream_t stream) {
    const float* inp   = (const float*)d_in[0];
    const float* W_ih  = (const float*)d_in[1];
    const float* W_hh  = (const float*)d_in[2];
    const float* b_mod = (const float*)d_in[3];
    const float* W_lin = (const float*)d_in[4];
    const float* b_lin = (const float*)d_in[5];
    float* out = (float*)d_out;

    dim3 grid(NBATCH / BPB);   // 512 blocks, one wave each (2 waves/CU)
    dim3 block(64);
    rnn_mfma1<<<grid, block, 0, stream>>>(inp, W_ih, W_hh, b_mod,
                                          W_lin, b_lin, out);
}